// Round 2
// baseline (330.730 us; speedup 1.0000x reference)
//
#include <hip/hip_runtime.h>

typedef __attribute__((ext_vector_type(4))) float v4f;
typedef __attribute__((ext_vector_type(8))) short v8s;
typedef __attribute__((ext_vector_type(4))) short v4s;
typedef __attribute__((ext_vector_type(2))) unsigned v2u;

// full RNE fp32->bf16 (used in prep kernels, cost-free there)
__device__ __forceinline__ short f2bf(float f) {
  union { float f; unsigned u; } v; v.f = f;
  unsigned r = v.u + 0x7FFFu + ((v.u >> 16) & 1u);
  return (short)(r >> 16);
}
__device__ __forceinline__ unsigned pk_rne(float a, float b) {
  return ((unsigned)(unsigned short)f2bf(a)) | (((unsigned)(unsigned short)f2bf(b)) << 16);
}
// round-half-up pack, 5 VALU ops / 2 values (hot epilogue only)
__device__ __forceinline__ unsigned pk_fast(float a, float b) {
  union { float f; unsigned u; } x, y; x.f = a; y.f = b;
  return ((x.u + 0x8000u) >> 16) | ((y.u + 0x8000u) & 0xFFFF0000u);
}

// Detect whether the index array is int64 (odd 32-bit words all zero) or int32.
__global__ void detect_i64(const unsigned* __restrict__ e, int* __restrict__ flag) {
  if (threadIdx.x == 0) {
    unsigned o = 0;
    for (int i = 0; i < 32; ++i) o |= e[2 * i + 1];
    *flag = (o == 0) ? 1 : 0;
  }
}

// Fused prep: pack W1/W2 into MFMA A-fragment order (transposed product, W^T as A)
// and (optionally) convert feature tables to bf16.
//   lane l of fragment (mt, kt) holds A'[n = mt*16 + (l&15)][k = kt*32 + (l>>4)*8 + j]
__global__ void pack_convert(const float* __restrict__ W1, const float* __restrict__ W2,
                             const float* __restrict__ xu, const float* __restrict__ xm,
                             short* __restrict__ pW1, short* __restrict__ pW2,
                             short* __restrict__ btab, int nxu, int nxm, int do_tables) {
  int tid = blockIdx.x * 256 + threadIdx.x;
  if (tid < 32768) {
    int j = tid & 7, l = (tid >> 3) & 63, frag = tid >> 9;
    int mt = frag >> 2, kt = frag & 3;
    int n = mt * 16 + (l & 15);
    int k = kt * 32 + ((l >> 4) * 8) + j;
    pW1[tid] = f2bf(W1[k * 256 + n]);
  } else if (tid < 98304) {
    int t2 = tid - 32768;
    int j = t2 & 7, l = (t2 >> 3) & 63, frag = t2 >> 9;
    int mt = frag >> 3, kt = frag & 7;
    int n = mt * 16 + (l & 15);
    int k = kt * 32 + ((l >> 4) * 8) + j;
    pW2[t2] = f2bf(W2[k * 256 + n]);
  } else if (do_tables) {
    int i = tid - 98304;                 // one float4 per thread
    int nq = (nxu + nxm) >> 2;
    if (i < nq) {
      int f0 = i << 2;
      v4f v = (f0 < nxu) ? *(const v4f*)(xu + f0) : *(const v4f*)(xm + (f0 - nxu));
      v2u r; r.x = pk_rne(v[0], v[1]); r.y = pk_rne(v[2], v[3]);
      *(v2u*)(btab + f0) = r;            // btab covers xu then xm contiguously
    }
  }
}

#define LDX_S 136   // 128 + 8 pad
#define LDH_S 264   // 256 + 8 pad

// Fused 3-layer MLP over a 64-edge tile. 256 threads = 4 waves.
// Wave w computes hidden rows [w*64, w*64+64) x all 64 edges (transposed GEMM:
// D[n_hidden][edge] = sum_k W[k][n] * X[edge][k]).
__global__ __launch_bounds__(256, 3) void mlp_fused(
    const float* __restrict__ xu, const float* __restrict__ xm,
    const short* __restrict__ bxu, const short* __restrict__ bxm, int use_bf16,
    const void* __restrict__ eidx_raw, const int* __restrict__ flag,
    const short* __restrict__ pW1, const short* __restrict__ pW2,
    const float* __restrict__ b1, const float* __restrict__ b2,
    const float* __restrict__ W3, const float* __restrict__ b3,
    float* __restrict__ out, int E)
{
  __shared__ __align__(16) short ldsX[64 * LDX_S];   // [edge][k0..127] bf16
  __shared__ __align__(16) short ldsH[64 * LDH_S];   // [edge][h0..255] bf16
  float* ldsPart = (float*)ldsX;                     // aliased: ldsX dead after layer 1

  const int t    = threadIdx.x;
  const int w    = t >> 6;        // wave 0..3 : hidden slice w*64
  const int lane = t & 63;
  const int quad = lane >> 4;
  const int lp   = lane & 15;

  // ---- preload bias/W3 fragments into registers (L1/L2-hot, broadcast per quad)
  v4f rb1[4], rb2[4], rw3[4];
#pragma unroll
  for (int mi = 0; mi < 4; ++mi) {
    int nh0 = w * 64 + mi * 16 + quad * 4;
    rb1[mi] = *(const v4f*)(b1 + nh0);
    rb2[mi] = *(const v4f*)(b2 + nh0);
    rw3[mi] = *(const v4f*)(W3 + nh0);
  }

  // ---- gather: 4 threads per edge, 16 feats (user) + 16 feats (movie) each
  {
    const int i = t >> 2, q = t & 3;
    int gE = blockIdx.x * 64 + i;
    if (gE >= E) gE = 0;
    int row, col;
    if (*flag) {
      const long long* p = (const long long*)eidx_raw;
      row = (int)p[gE]; col = (int)p[(long long)E + gE];
    } else {
      const int* p = (const int*)eidx_raw;
      row = p[gE]; col = p[E + gE];
    }
    short* px = &ldsX[i * LDX_S + q * 16];
    if (use_bf16) {
      const v8s* pu = (const v8s*)(bxu + (size_t)row * 64 + q * 16);
      const v8s* pm = (const v8s*)(bxm + (size_t)col * 64 + q * 16);
      v8s u0 = pu[0], u1 = pu[1], m0 = pm[0], m1 = pm[1];
      *(v8s*)(px)      = u0; *(v8s*)(px + 8)  = u1;   // user -> k 0..63
      *(v8s*)(px + 64) = m0; *(v8s*)(px + 72) = m1;   // movie -> k 64..127
    } else {
      const v4f* pu = (const v4f*)(xu + (long long)row * 64 + q * 16);
      const v4f* pm = (const v4f*)(xm + (long long)col * 64 + q * 16);
      v4f U[4], M[4];
#pragma unroll
      for (int s = 0; s < 4; ++s) { U[s] = pu[s]; M[s] = pm[s]; }
      v8s u0, u1, m0, m1;
#pragma unroll
      for (int c = 0; c < 4; ++c) {
        u0[c] = f2bf(U[0][c]); u0[c + 4] = f2bf(U[1][c]);
        u1[c] = f2bf(U[2][c]); u1[c + 4] = f2bf(U[3][c]);
        m0[c] = f2bf(M[0][c]); m0[c + 4] = f2bf(M[1][c]);
        m1[c] = f2bf(M[2][c]); m1[c + 4] = f2bf(M[3][c]);
      }
      *(v8s*)(px)      = u0; *(v8s*)(px + 8)  = u1;
      *(v8s*)(px + 64) = m0; *(v8s*)(px + 72) = m1;
    }
  }
  __syncthreads();

  // ---- layer 1: D1[n][e] over K=128 (4 k-steps)
  v4f acc[4][4] = {};
  const v8s* w1v = (const v8s*)pW1;
#pragma unroll
  for (int kt = 0; kt < 4; ++kt) {
    v8s a[4], b[4];
#pragma unroll
    for (int mi = 0; mi < 4; ++mi)
      a[mi] = w1v[(((w * 4 + mi) * 4) + kt) * 64 + lane];
#pragma unroll
    for (int ni = 0; ni < 4; ++ni)
      b[ni] = *(const v8s*)&ldsX[(ni * 16 + lp) * LDX_S + kt * 32 + quad * 8];
#pragma unroll
    for (int mi = 0; mi < 4; ++mi)
#pragma unroll
      for (int ni = 0; ni < 4; ++ni)
        acc[mi][ni] = __builtin_amdgcn_mfma_f32_16x16x32_bf16(a[mi], b[ni], acc[mi][ni], 0, 0, 0);
  }

  // ---- epilogue 1: bias + relu + bf16 -> ldsH[e][n]
#pragma unroll
  for (int mi = 0; mi < 4; ++mi) {
    int nh0 = w * 64 + mi * 16 + quad * 4;          // 4 consecutive hidden dims
#pragma unroll
    for (int ni = 0; ni < 4; ++ni) {
      int e = ni * 16 + lp;
      v4f v = acc[mi][ni] + rb1[mi];
      float x0 = v[0] > 0.f ? v[0] : 0.f;
      float x1 = v[1] > 0.f ? v[1] : 0.f;
      float x2 = v[2] > 0.f ? v[2] : 0.f;
      float x3 = v[3] > 0.f ? v[3] : 0.f;
      v2u pw; pw.x = pk_fast(x0, x1); pw.y = pk_fast(x2, x3);
      *(v2u*)&ldsH[e * LDH_S + nh0] = pw;           // ds_write_b64
    }
  }
  __syncthreads();

  // ---- layer 2: D2[n][e] over K=256 (8 k-steps)
  v4f acc2[4][4] = {};
  const v8s* w2v = (const v8s*)pW2;
#pragma unroll
  for (int kt = 0; kt < 8; ++kt) {
    v8s a[4], b[4];
#pragma unroll
    for (int mi = 0; mi < 4; ++mi)
      a[mi] = w2v[(((w * 4 + mi) * 8) + kt) * 64 + lane];
#pragma unroll
    for (int ni = 0; ni < 4; ++ni)
      b[ni] = *(const v8s*)&ldsH[(ni * 16 + lp) * LDH_S + kt * 32 + quad * 8];
#pragma unroll
    for (int mi = 0; mi < 4; ++mi)
#pragma unroll
      for (int ni = 0; ni < 4; ++ni)
        acc2[mi][ni] = __builtin_amdgcn_mfma_f32_16x16x32_bf16(a[mi], b[ni], acc2[mi][ni], 0, 0, 0);
  }

  // ---- layer 3 (fp32): s[e] += relu(h2 + b2) . W3, per-lane partials
  float s[4] = {0.f, 0.f, 0.f, 0.f};
#pragma unroll
  for (int mi = 0; mi < 4; ++mi) {
#pragma unroll
    for (int ni = 0; ni < 4; ++ni) {
      v4f v = acc2[mi][ni] + rb2[mi];
#pragma unroll
      for (int r = 0; r < 4; ++r) {
        float x = v[r] > 0.f ? v[r] : 0.f;
        s[ni] += x * rw3[mi][r];
      }
    }
  }
#pragma unroll
  for (int ni = 0; ni < 4; ++ni) {
    int e = ni * 16 + lp;
    ldsPart[e * 16 + w * 4 + quad] = s[ni];
  }
  __syncthreads();

  // ---- final reduce: 16 partials per edge
  if (t < 64) {
    const v4f* pp = (const v4f*)&ldsPart[t * 16];
    v4f p0 = pp[0], p1 = pp[1], p2 = pp[2], p3 = pp[3];
    float r = b3[0]
            + (p0[0] + p0[1] + p0[2] + p0[3]) + (p1[0] + p1[1] + p1[2] + p1[3])
            + (p2[0] + p2[1] + p2[2] + p2[3]) + (p3[0] + p3[1] + p3[2] + p3[3]);
    int o = blockIdx.x * 64 + t;
    if (o < E) out[o] = r;
  }
}

extern "C" void kernel_launch(void* const* d_in, const int* in_sizes, int n_in,
                              void* d_out, int out_size, void* d_ws, size_t ws_size,
                              hipStream_t stream) {
  const float* xu  = (const float*)d_in[0];
  const float* xm  = (const float*)d_in[1];
  const void*  ei  = d_in[2];
  const float* W1  = (const float*)d_in[3];
  const float* b1  = (const float*)d_in[4];
  const float* W2  = (const float*)d_in[5];
  const float* b2  = (const float*)d_in[6];
  const float* W3  = (const float*)d_in[7];
  const float* b3  = (const float*)d_in[8];
  float* out = (float*)d_out;

  const int E   = in_sizes[2] / 2;
  const int nxu = in_sizes[0];
  const int nxm = in_sizes[1];

  // ws layout: flag@0 (16B), pW1@16 (64KB), pW2@65552 (128KB), btab@196624 (bf16 tables)
  char* ws = (char*)d_ws;
  int*   flag = (int*)ws;
  short* pW1  = (short*)(ws + 16);
  short* pW2  = (short*)(ws + 16 + 65536);
  short* btab = (short*)(ws + 16 + 65536 + 131072);
  const size_t need_tab = 16 + 65536 + 131072 + (size_t)(nxu + nxm) * 2;
  const int use_bf16 = (ws_size >= need_tab) ? 1 : 0;

  hipLaunchKernelGGL(detect_i64, dim3(1), dim3(64), 0, stream, (const unsigned*)ei, flag);

  const int prep_items = 98304 + (use_bf16 ? ((nxu + nxm) >> 2) : 0);
  hipLaunchKernelGGL(pack_convert, dim3((prep_items + 255) / 256), dim3(256), 0, stream,
                     W1, W2, xu, xm, pW1, pW2, btab, nxu, nxm, use_bf16);

  const short* bxu = btab;
  const short* bxm = btab + nxu;
  const int nblocks = (E + 63) / 64;
  hipLaunchKernelGGL(mlp_fused, dim3(nblocks), dim3(256), 0, stream,
                     xu, xm, bxu, bxm, use_bf16, ei, flag, pW1, pW2,
                     b1, b2, W3, b3, out, E);
}